// Round 11
// baseline (197.964 us; speedup 1.0000x reference)
//
#include <hip/hip_runtime.h>
#include <hip/hip_bf16.h>

// MultiHeadAttention: B=2, S=2048, D=1024, H=16, hd=64, causal, fp32 I/O.
//   k0: fused convert x + 4 weights -> bf16 (1 launch)
//   k1: fused QKV GEMM: 256x256 tile, 8 waves, BK=32, ring-3 LDS, counted vmcnt(4),
//       2-PHASE per K-step (stage || ds_read || MFMA fine interleave, setprio) -> Q,K,V^T
//   k2: causal flash, paired q-tiles share staged K/V; max-free softmax; setprio
//   k3: out-proj GEMM (dbuf 2-phase, 128x64 tiles, 512 blocks) -> fp32

typedef __attribute__((ext_vector_type(8))) short short8;
typedef __attribute__((ext_vector_type(4))) float f32x4;
typedef __attribute__((ext_vector_type(8))) unsigned short u16x8;
typedef __attribute__((ext_vector_type(4))) unsigned short u16x4;

#define QSCALE 0.1803368801111244f   // (1/sqrt(64)) * log2(e)
#define MFMA16(a, b, c) __builtin_amdgcn_mfma_f32_16x16x32_bf16(a, b, c, 0, 0, 0)

__device__ __forceinline__ unsigned short f2bf(float f) {
  unsigned int u = __float_as_uint(f);
  u += 0x7fffu + ((u >> 16) & 1u);   // RNE
  return (unsigned short)(u >> 16);
}

__device__ __forceinline__ void gload_lds16(const void* g, void* l) {
  __builtin_amdgcn_global_load_lds(
      (const __attribute__((address_space(1))) unsigned int*)g,
      (__attribute__((address_space(3))) unsigned int*)l, 16, 0, 0);
}

// ---------------- fused convert fp32 -> bf16 ----------------
__global__ __launch_bounds__(256) void convert_all_kernel(
    const float* __restrict__ x, const float* __restrict__ wq,
    const float* __restrict__ wk, const float* __restrict__ wv,
    const float* __restrict__ wo, unsigned short* __restrict__ xb,
    unsigned short* __restrict__ wqkv, unsigned short* __restrict__ wob) {
  const int b = blockIdx.x, tid = threadIdx.x;
  const float* src;
  unsigned short* dst;
  int i;
  if (b < 4096) { src = x; dst = xb; i = b * 256 + tid; }
  else {
    const int r = b - 4096, seg = r >> 10;
    i = (r & 1023) * 256 + tid;
    src = seg == 0 ? wq : (seg == 1 ? wk : (seg == 2 ? wv : wo));
    dst = seg == 3 ? wob : wqkv + (size_t)seg * 1048576;
  }
  float4 v = ((const float4*)src)[i];
  u16x4 o = {f2bf(v.x), f2bf(v.y), f2bf(v.z), f2bf(v.w)};
  *(u16x4*)(dst + (size_t)i * 4) = o;
}

// ---------------- fused QKV projection: 256x256, ring-3, counted vmcnt, 2-phase ----------------
// C[4096 x 3072] = xb[4096x1024] * wqkv[3072x1024]^T.  512 threads = 8 waves (2M x 4N).
// Ring-3 K-tile slots (BK=32): compute slot t%3 while staging tile t+2 into (t+2)%3.
// Ledger (per wave): 4 loads/K-step; before K-step's final barrier: vmcnt(4) ->
// tile t+1's 4 loads complete, tile t+2's 4 stay in flight ACROSS the barrier.
// Each K-step is split into 2 phases {stage 2 || ds_read || barrier; lgkm0; SB0;
// prio1; 16 MFMA; prio0; barrier} so waves interleave LDS/VMEM/MFMA roles (T3+T5).
__global__ __launch_bounds__(512, 2) void gemm_qkv_kernel(
    const unsigned short* __restrict__ xb, const unsigned short* __restrict__ wqkv,
    const float* __restrict__ bq, const float* __restrict__ bk, const float* __restrict__ bv,
    unsigned short* __restrict__ Qb, unsigned short* __restrict__ Kb,
    unsigned short* __restrict__ VTb) {
  __shared__ unsigned short As[3 * 256 * 32];   // 48 KiB: 3 slots of [256 rows][32 k]
  __shared__ unsigned short Bs[3 * 256 * 32];   // 48 KiB

  const int tid = threadIdx.x;
  const int w = tid >> 6, l = tid & 63;
  const int wm = w >> 2, wn = w & 3;            // 2 x 4 wave grid
  const int rl = l & 15, hi = l >> 4;

  // bm-major XCD chunking: XCD g owns bm {2g, 2g+1} x all 12 bn (A panels L2-resident)
  const int wg = (blockIdx.x & 7) * 24 + (blockIdx.x >> 3);  // bijective, 192 = 8*24
  const int bm = wg / 12, bn = wg % 12;
  const int tm = bm * 256, tn = bn * 256;

  // staging: load c covers rows c*128 + tid/4, 16B chunk (tid&3) of a 64B row
  const unsigned short* Ag = xb + (size_t)(tm + (tid >> 2)) * 1024 + (tid & 3) * 8;
  const unsigned short* Bg = wqkv + (size_t)(tn + (tid >> 2)) * 1024 + (tid & 3) * 8;
  const int wst = w * 512;                      // wave-uniform LDS stage base (elems)

  f32x4 acc[8][4] = {};

  // prologue: stage tiles 0,1 fully; wait tile 0 (tile 1's 4 stay in flight)
  {
    gload_lds16(Ag, As + wst);
    gload_lds16(Ag + 128 * 1024, As + 4096 + wst);
    gload_lds16(Bg, Bs + wst);
    gload_lds16(Bg + 128 * 1024, Bs + 4096 + wst);
    gload_lds16(Ag + 32, As + 8192 + wst);
    gload_lds16(Ag + 128 * 1024 + 32, As + 8192 + 4096 + wst);
    gload_lds16(Bg + 32, Bs + 8192 + wst);
    gload_lds16(Bg + 128 * 1024 + 32, Bs + 8192 + 4096 + wst);
  }
  asm volatile("s_waitcnt vmcnt(4)" ::: "memory");
  __builtin_amdgcn_s_barrier();
  asm volatile("" ::: "memory");

  const int abase = (wm * 128 + rl) * 32 + hi * 8;   // + m*16*32 per mrep
  const int bbase = (wn * 64 + rl) * 32 + hi * 8;    // + n*16*32 per nrep

  int sl = 0, sn = 2;
  for (int t = 0; t < 32; ++t) {
    const unsigned short* Ap = As + sl * 8192;
    const unsigned short* Bp = Bs + sl * 8192;

    // ---- phase 1: stage A(t+2); read B0-3 + A0-3; MFMA m0-3 x n0-3 ----
    if (t < 30) {
      const int k0 = (t + 2) * 32;
      gload_lds16(Ag + k0, As + sn * 8192 + wst);
      gload_lds16(Ag + 128 * 1024 + k0, As + sn * 8192 + 4096 + wst);
    }
    short8 bfr[4], afr[4];
#pragma unroll
    for (int n = 0; n < 4; ++n) bfr[n] = *(const short8*)&Bp[bbase + n * 512];
#pragma unroll
    for (int m = 0; m < 4; ++m) afr[m] = *(const short8*)&Ap[abase + m * 512];
    __builtin_amdgcn_s_barrier();
    asm volatile("s_waitcnt lgkmcnt(0)" ::: "memory");
    __builtin_amdgcn_sched_barrier(0);
    __builtin_amdgcn_s_setprio(1);
#pragma unroll
    for (int m = 0; m < 4; ++m)
#pragma unroll
      for (int n = 0; n < 4; ++n)
        acc[m][n] = MFMA16(afr[m], bfr[n], acc[m][n]);
    __builtin_amdgcn_s_setprio(0);
    __builtin_amdgcn_s_barrier();

    // ---- phase 2: stage B(t+2); read A4-7; MFMA m4-7 x n0-3 (reuse bfr) ----
    if (t < 30) {
      const int k0 = (t + 2) * 32;
      gload_lds16(Bg + k0, Bs + sn * 8192 + wst);
      gload_lds16(Bg + 128 * 1024 + k0, Bs + sn * 8192 + 4096 + wst);
    }
    short8 afr2[4];
#pragma unroll
    for (int m = 0; m < 4; ++m) afr2[m] = *(const short8*)&Ap[abase + (m + 4) * 512];
    __builtin_amdgcn_s_barrier();
    asm volatile("s_waitcnt lgkmcnt(0)" ::: "memory");
    __builtin_amdgcn_sched_barrier(0);
    __builtin_amdgcn_s_setprio(1);
#pragma unroll
    for (int m = 0; m < 4; ++m)
#pragma unroll
      for (int n = 0; n < 4; ++n)
        acc[m + 4][n] = MFMA16(afr2[m], bfr[n], acc[m + 4][n]);
    __builtin_amdgcn_s_setprio(0);
    // K-step handoff: tile t+1 complete, tile t+2 stays in flight across barrier
    if (t < 30) asm volatile("s_waitcnt vmcnt(4)" ::: "memory");
    else        asm volatile("s_waitcnt vmcnt(0)" ::: "memory");
    __builtin_amdgcn_s_barrier();
    sl = (sl == 2) ? 0 : sl + 1;
    sn = (sn == 2) ? 0 : sn + 1;
  }

  // epilogue: proj uniform per tile (tn multiple of 256, boundaries at 1024/2048)
  const int proj = tn >> 10;
  const float* bias = proj == 0 ? bq : (proj == 1 ? bk : bv);
#pragma unroll
  for (int m = 0; m < 8; ++m) {
    const int row0 = tm + wm * 128 + m * 16 + hi * 4;   // token index, %4 == 0
    const int b2 = row0 >> 11, s2 = row0 & 2047;
#pragma unroll
    for (int n = 0; n < 4; ++n) {
      const int col = (tn & 1023) + wn * 64 + n * 16 + rl;  // within-proj col
      const int h = col >> 6, d = col & 63;
      const float bi = bias[col];
      if (proj == 2) {
        u16x4 pv = {f2bf(acc[m][n][0] + bi), f2bf(acc[m][n][1] + bi),
                    f2bf(acc[m][n][2] + bi), f2bf(acc[m][n][3] + bi)};
        *(u16x4*)&VTb[((size_t)((b2 * 16 + h) * 64 + d)) * 2048 + s2] = pv;
      } else {
        const float sc = (proj == 0) ? QSCALE : 1.0f;
        unsigned short* dst = (proj == 0) ? Qb : Kb;
#pragma unroll
        for (int i = 0; i < 4; ++i)
          dst[((size_t)(b2 * 16 + h) * 2048 + (s2 + i)) * 64 + d] =
              f2bf((acc[m][n][i] + bi) * sc);
      }
    }
  }
}

// ---------------- double-buffered GEMM mainloop (C = A * B^T), K=1024 ----------------
// (used by gemm_out only)
template<int NF>
__device__ __forceinline__ void gemm_db_mainloop(
    const unsigned short* __restrict__ A, const unsigned short* __restrict__ B,
    int tm, int tn, unsigned short* As0, unsigned short* Bs0,
    f32x4 (&acc)[4][NF]) {
  constexpr int BN = NF * 32;
  const int tid = threadIdx.x;
  const int w = tid >> 6, l = tid & 63;
  const int wr = (w >> 1) * 64, wc = (w & 1) * (BN / 2);
  const int srow = l >> 2;
  const int schunk = (l & 3) * 8;
  const int rl = l & 15, kl = (l >> 4) * 8;
  const int K = 1024;
  unsigned short* As1 = As0 + 128 * 32;
  unsigned short* Bs1 = Bs0 + BN * 32;

#define STAGE_TILE(AP, BP, KOFF)                                               \
  {                                                                            \
    _Pragma("unroll") for (int c = 0; c < 2; ++c) {                            \
      const int rowb = w * 32 + c * 16;                                        \
      gload_lds16(A + (size_t)(tm + rowb + srow) * K + (KOFF) + schunk,        \
                  (AP) + rowb * 32);                                           \
    }                                                                          \
    _Pragma("unroll") for (int c = 0; c < BN / 64; ++c) {                      \
      const int rowb = w * (BN / 4) + c * 16;                                  \
      gload_lds16(B + (size_t)(tn + rowb + srow) * K + (KOFF) + schunk,        \
                  (BP) + rowb * 32);                                           \
    }                                                                          \
  }

  STAGE_TILE(As0, Bs0, 0)
  __syncthreads();
  int p = 0;
  for (int k0 = 0; k0 < K; k0 += 32) {
    unsigned short* Ac = p ? As1 : As0;
    unsigned short* Bc = p ? Bs1 : Bs0;
    if (k0 + 32 < K) {
      unsigned short* An = p ? As0 : As1;
      unsigned short* Bn = p ? Bs0 : Bs1;
      STAGE_TILE(An, Bn, k0 + 32)
    }
    short8 af[4], bf[NF];
#pragma unroll
    for (int m = 0; m < 4; ++m) af[m] = *(const short8*)&Ac[(wr + m * 16 + rl) * 32 + kl];
#pragma unroll
    for (int n = 0; n < NF; ++n) bf[n] = *(const short8*)&Bc[(wc + n * 16 + rl) * 32 + kl];
#pragma unroll
    for (int m = 0; m < 4; ++m)
#pragma unroll
      for (int n = 0; n < NF; ++n)
        acc[m][n] = MFMA16(af[m], bf[n], acc[m][n]);
    __syncthreads();
    p ^= 1;
  }
#undef STAGE_TILE
}

// ---------------- flash attention helpers ----------------
template<bool DIAG>
__device__ __forceinline__ void softmax_pack(
    const f32x4 s[4], float& l_i, char* ps,
    int rl, int hi, int swz, int qrow, int kv0) {
  float p[4][4];
  float rs = 0.f;
#pragma unroll
  for (int f = 0; f < 4; ++f)
#pragma unroll
    for (int i = 0; i < 4; ++i) {
      float sv = s[f][i];
      if (DIAG) sv = (kv0 + f * 16 + hi * 4 + i <= qrow) ? sv : -1e30f;
      const float e = __builtin_amdgcn_exp2f(sv);
      p[f][i] = e;
      rs += e;
    }
  rs += __shfl_xor(rs, 16, 64);
  rs += __shfl_xor(rs, 32, 64);
  l_i += rs;
#pragma unroll
  for (int f = 0; f < 4; ++f) {
    u16x4 pv = {f2bf(p[f][0]), f2bf(p[f][1]), f2bf(p[f][2]), f2bf(p[f][3])};
    *(u16x4*)(ps + rl * 128 + ((f * 32 + hi * 8) ^ swz)) = pv;
  }
}

template<bool L_ON, bool L_DIAG, bool H_DIAG>
__device__ __forceinline__ void attn_stage(
    const char* kb, const char* vb, char* psH, char* psL,
    const short8 qfH[2], const short8 qfL[2],
    f32x4 oH[4], f32x4 oL[4], float& lH, float& lL,
    int rl, int hi, int swz, int qrH, int qrL, int kv0, int w) {
  const int fvH = H_DIAG ? (w + 1) : 4;
  f32x4 sH[4] = {}, sL[4] = {};
  __builtin_amdgcn_s_setprio(1);
#pragma unroll
  for (int f = 0; f < 4; ++f) {
    if (H_DIAG && f >= fvH) continue;
    const char* rowp = kb + (f * 16 + rl) * 128;
#pragma unroll
    for (int kc = 0; kc < 2; ++kc) {
      short8 kf = *(const short8*)(rowp + ((kc * 64 + hi * 16) ^ swz));
      sH[f] = MFMA16(kf, qfH[kc], sH[f]);
      if (L_ON && (!L_DIAG || f < w + 1)) sL[f] = MFMA16(kf, qfL[kc], sL[f]);
    }
  }
  __builtin_amdgcn_s_setprio(0);
  softmax_pack<H_DIAG>(sH, lH, psH, rl, hi, swz, qrH, kv0);
  if (L_ON) softmax_pack<L_DIAG>(sL, lL, psL, rl, hi, swz, qrL, kv0);

  const int kcvH = H_DIAG ? ((w >= 2) ? 2 : 1) : 2;
  const int kcvL = (L_ON && L_DIAG) ? ((w >= 2) ? 2 : 1) : 2;
  __builtin_amdgcn_s_setprio(1);
#pragma unroll
  for (int kc = 0; kc < 2; ++kc) {
    if (H_DIAG && kc >= kcvH) continue;
    short8 paH = *(const short8*)(psH + rl * 128 + ((kc * 64 + hi * 16) ^ swz));
    const bool lpv = L_ON && kc < kcvL;
    short8 paL = {};
    if (lpv) paL = *(const short8*)(psL + rl * 128 + ((kc * 64 + hi * 16) ^ swz));
#pragma unroll
    for (int fd = 0; fd < 4; ++fd) {
      short8 vf = *(const short8*)(vb + (fd * 16 + rl) * 128 + ((kc * 64 + hi * 16) ^ swz));
      oH[fd] = MFMA16(vf, paH, oH[fd]);
      if (lpv) oL[fd] = MFMA16(vf, paL, oL[fd]);
    }
  }
  __builtin_amdgcn_s_setprio(0);
}

// ---------------- causal flash attention ----------------
__global__ __launch_bounds__(256) void flash_kernel(
    const unsigned short* __restrict__ Q, const unsigned short* __restrict__ K,
    const unsigned short* __restrict__ VT, unsigned short* __restrict__ AO) {
  __shared__ unsigned short KbS[2][64 * 64];
  __shared__ unsigned short VbS[2][64 * 64];
  __shared__ unsigned short PsS[4][2][16 * 64];

  const int tid = threadIdx.x;
  const int w = tid >> 6, l = tid & 63;
  const int rl = l & 15, hi = l >> 4;
  const int swz = (rl & 7) << 4;
  const int bid = blockIdx.x;
  const int g = bid & 7, r = bid >> 3;
  const int bh = g * 4 + (r & 3);
  const int pr = r >> 2;                    // 0..15
  const int qtH = 31 - pr, qtL = pr;
  const size_t head_off = (size_t)bh * 2048 * 64;

  const int qrH = qtH * 64 + w * 16 + rl;
  const int qrL = qtL * 64 + w * 16 + rl;

  short8 qfH[2], qfL[2];
  {
    const unsigned short* qp = Q + head_off + (size_t)qrH * 64 + hi * 8;
    qfH[0] = *(const short8*)qp;
    qfH[1] = *(const short8*)(qp + 32);
    qp = Q + head_off + (size_t)qrL * 64 + hi * 8;
    qfL[0] = *(const short8*)qp;
    qfL[1] = *(const short8*)(qp + 32);
  }

  f32x4 oH[4] = {}, oL[4] = {};
  float lH = 0.f, lL = 0.f;

  const int sr = tid >> 2;
  const int swzW = (sr & 7) << 4;
  const int cb0 = (tid & 3) * 32;
  const int kwoff0 = sr * 128 + (cb0 ^ swzW);
  const int kwoff1 = sr * 128 + ((cb0 + 16) ^ swzW);
  const unsigned short* kbase = K + head_off + (size_t)sr * 64 + (tid & 3) * 16;
  const unsigned short* vbase = VT + ((size_t)(bh * 64 + sr)) * 2048 + (tid & 3) * 16;

  u16x8 kra = *(const u16x8*)kbase;
  u16x8 krb = *(const u16x8*)(kbase + 8);
  u16x8 vra = *(const u16x8*)vbase;
  u16x8 vrb = *(const u16x8*)(vbase + 8);
  {
    char* kd = (char*)KbS;
    char* vd = (char*)VbS;
    *(u16x8*)(kd + kwoff0) = kra;
    *(u16x8*)(kd + kwoff1) = krb;
    *(u16x8*)(vd + kwoff0) = vra;
    *(u16x8*)(vd + kwoff1) = vrb;
  }
  kra = *(const u16x8*)(kbase + 4096);
  krb = *(const u16x8*)(kbase + 4096 + 8);
  vra = *(const u16x8*)(vbase + 64);
  vrb = *(const u16x8*)(vbase + 64 + 8);
  __syncthreads();

  char* psH = (char*)&PsS[w][0][0];
  char* psL = (char*)&PsS[w][1][0];

  for (int t = 0; t <= qtH; ++t) {
    const int cur = t & 1;
    const char* kb = (const char*)KbS + cur * 8192;
    const char* vb = (const char*)VbS + cur * 8192;
    const int kv0 = t * 64;

    if (t < qtL)
      attn_stage<true, false, false>(kb, vb, psH, psL, qfH, qfL, oH, oL, lH, lL,
                                     rl, hi, swz, qrH, qrL, kv0, w);
    else if (t == qtL)
      attn_stage<true, true, false>(kb, vb, psH, psL, qfH, qfL, oH, oL, lH, lL,
                                    rl, hi, swz, qrH, qrL, kv0, w);
    else if (t < qtH)
      attn_stage<false, false, false>(kb, vb, psH, psL, qfH, qfL, oH, oL, lH, lL,
                                      rl, hi, swz, qrH, qrL, kv0, w);
    else
      attn_stage<false, false, true>(kb, vb, psH, psL, qfH, qfL, oH, oL, lH, lL,
                                     rl, hi, swz, qrH, qrL, kv0, w);

    if (t < qtH) {
      char* kd = (char*)KbS + (cur ^ 1) * 8192;
      char* vd = (char*)VbS + (cur ^ 1) * 8192;
      *(u16x8*)(kd + kwoff0) = kra;
      *(u16x8*)(kd + kwoff1) = krb;
      *(u16x8*)(vd + kwoff0) = vra;
      *(u16x8*)(vd + kwoff1) = vrb;
      if (t + 2 <= qtH) {
        const size_t ko = (size_t)(t + 2) * 4096;
        kra = *(const u16x8*)(kbase + ko);
        krb = *(const u16x8*)(kbase + ko + 8);
        vra = *(const u16x8*)(vbase + (t + 2) * 64);
        vrb = *(const u16x8*)(vbase + (t + 2) * 64 + 8);
      }
    }
    __syncthreads();
  }

  const float invH = 1.f / lH, invL = 1.f / lL;
  const size_t orowH = (size_t)(bh >> 4) * 2048 + qrH;
  const size_t orowL = (size_t)(bh >> 4) * 2048 + qrL;
  const int hcol = (bh & 15) * 64;
#pragma unroll
  for (int fd = 0; fd < 4; ++fd) {
    u16x4 a = {f2bf(oH[fd][0] * invH), f2bf(oH[fd][1] * invH),
               f2bf(oH[fd][2] * invH), f2bf(oH[fd][3] * invH)};
    *(u16x4*)&AO[orowH * 1024 + hcol + fd * 16 + hi * 4] = a;
    u16x4 b = {f2bf(oL[fd][0] * invL), f2bf(oL[fd][1] * invL),
               f2bf(oL[fd][2] * invL), f2bf(oL[fd][3] * invL)};
    *(u16x4*)&AO[orowL * 1024 + hcol + fd * 16 + hi * 4] = b;
  }
}

// ---------------- output projection -> fp32 (128x64 tiles, 512 blocks) ----------------
__global__ __launch_bounds__(256) void gemm_out_kernel(
    const unsigned short* __restrict__ AOb, const unsigned short* __restrict__ wob,
    const float* __restrict__ bo, float* __restrict__ out) {
  __shared__ unsigned short As[2 * 128 * 32], Bs[2 * 64 * 32];
  f32x4 acc[4][2] = {};
  const int flat = blockIdx.x;
  const int xcd = flat & 7, loc = flat >> 3;
  const int bn = xcd * 2 + (loc & 1), bm = loc >> 1;
  const int tm = bm * 128, tn = bn * 64;
  gemm_db_mainloop<2>(AOb, wob, tm, tn, As, Bs, acc);
  const int tid = threadIdx.x, w = tid >> 6, l = tid & 63;
  const int wr = (w >> 1) * 64, wc = (w & 1) * 32;
  const int rl = l & 15, hi = l >> 4;
#pragma unroll
  for (int m = 0; m < 4; ++m) {
    const int row0 = tm + wr + m * 16 + hi * 4;
#pragma unroll
    for (int n = 0; n < 2; ++n) {
      const int col = tn + wc + n * 16 + rl;
      const float bo_ = bo[col];
#pragma unroll
      for (int i = 0; i < 4; ++i)
        out[(size_t)(row0 + i) * 1024 + col] = acc[m][n][i] + bo_;
    }
  }
}

extern "C" void kernel_launch(void* const* d_in, const int* in_sizes, int n_in,
                              void* d_out, int out_size, void* d_ws, size_t ws_size,
                              hipStream_t stream) {
  const float* x  = (const float*)d_in[0];
  const float* Wq = (const float*)d_in[1];
  const float* bq = (const float*)d_in[2];
  const float* Wk = (const float*)d_in[3];
  const float* bk = (const float*)d_in[4];
  const float* Wv = (const float*)d_in[5];
  const float* bv = (const float*)d_in[6];
  const float* Wo = (const float*)d_in[7];
  const float* bo = (const float*)d_in[8];
  float* out = (float*)d_out;

  unsigned short* ws = (unsigned short*)d_ws;
  unsigned short* XB   = ws;                 // 4M elems, reused as AO
  unsigned short* WQKV = ws + 4194304;       // 3M
  unsigned short* WOB  = ws + 7340032;       // 1M
  unsigned short* QB   = ws + 8388608;       // 4M
  unsigned short* KB   = ws + 12582912;      // 4M
  unsigned short* VTB  = ws + 16777216;      // 4M (transposed V)
  unsigned short* AOB  = XB;

  convert_all_kernel<<<8192, 256, 0, stream>>>(x, Wq, Wk, Wv, Wo, XB, WQKV, WOB);
  gemm_qkv_kernel<<<192, 512, 0, stream>>>(XB, WQKV, bq, bk, bv, QB, KB, VTB);
  flash_kernel<<<512, 256, 0, stream>>>(QB, KB, VTB, AOB);
  gemm_out_kernel<<<512, 256, 0, stream>>>(AOB, WOB, bo, out);
}